// Round 4
// baseline (270.162 us; speedup 1.0000x reference)
//
#include <hip/hip_runtime.h>

// Fully fused 100x100 sliding mean: x[32][1][1124][1124] f32 -> out[32][1][1025][1025] f32.
// One kernel. Each block: 205 output cols x <=171 output rows. Horizontal 100-sums
// computed in LDS per input row (two-level partial sums), banked in an f16 ring
// (104 slots x 208 cols); vertical 100-sum = per-thread register running sum over
// the ring. The f32 intermediate never touches HBM.
//
// f16 ring precision: hsum ~ N(0,100) -> rel err ~5e-4 -> abs ~5e-2 per term;
// after 100-row sum (rms ~10x) and 1e-4 scale: ~1e-5 error << 1.06e-3 threshold
// (empirically identical absmax to the f32 path in rounds 1-3).

#define H_IN   1124
#define W_IN   1124
#define KWIN   100
#define W_OUT  1025
#define H_OUT  1025
#define NSTRIP 5
#define SW     205     // output cols per strip (5*205 = 1025)
#define NBAND  6
#define BR     171     // output rows per band (6*171=1026, last band 170)
#define NF4    78      // float4 staged per row (covers 312 floats >= 304+d+pad)
#define SR4    81      // srow4 row stride in float4 (pad: 324 words, +4 banks/row)
#define RSLOT  104     // ring slots (>= 100 + chunk of 4)
#define RCOL   208     // ring cols (205 used)

__global__ __launch_bounds__(256) void fused_box_kernel(
    const float* __restrict__ x, float* __restrict__ out)
{
    __shared__ float4   srow4[4][SR4];   // 5184 B
    __shared__ float    ps[4][80];       // 1280 B (78 used; sums of 4)
    __shared__ float    pps[4][20];      // 320 B (19 used; sums of 16)
    __shared__ _Float16 ring[RSLOT][RCOL]; // 43264 B

    const int tid   = threadIdx.x;
    const int strip = blockIdx.x;
    const int band  = blockIdx.y;
    const int b     = blockIdx.z;

    const int c0    = strip * SW;
    const int c0a4  = (c0 & ~3) >> 2;            // aligned float4 base index
    const int d     = c0 & 3;                    // misalignment 0..3
    const int r0    = band * BR;                 // first output row
    const int r1    = min(r0 + BR, H_OUT);       // exclusive
    const int r1_in = r1 + KWIN - 1;             // exclusive input-row bound

    const float4* x4 = (const float4*)(x + (size_t)b * H_IN * W_IN);  // row = 281 f4
    const float scale = 1.0f / (float)(KWIN * KWIN);

    // ---- prologue: stage chunk 0 (input rows r0..r0+3) ----
    for (int i = tid; i < 4 * NF4; i += 256) {
        int q = i / NF4, j = i - q * NF4;
        int r = r0 + q;
        if (r < r1_in) {
            int gj = c0a4 + j; gj = gj > 280 ? 280 : gj;   // stay inside the row
            srow4[q][j] = x4[(size_t)r * 281 + gj];
        }
    }
    __syncthreads();

    float4 pf0 = make_float4(0.f,0.f,0.f,0.f);
    float4 pf1 = make_float4(0.f,0.f,0.f,0.f);
    float  s   = 0.f;                            // vertical running sum (col = tid)

    for (int ra = r0; ra < r1_in; ra += 4) {
        const int rb = ra + 4;

        // 1. issue prefetch of next chunk into registers (lands under compute)
        if (rb < r1_in) {
            if (tid < 4 * NF4) {
                int q = tid / NF4, j = tid - q * NF4;
                int r = rb + q;
                int gj = c0a4 + j; gj = gj > 280 ? 280 : gj;
                if (r < r1_in) pf0 = x4[(size_t)r * 281 + gj];
            }
            int i1 = tid + 256;
            if (i1 < 4 * NF4) {
                int q = i1 / NF4, j = i1 - q * NF4;
                int r = rb + q;
                int gj = c0a4 + j; gj = gj > 280 ? 280 : gj;
                if (r < r1_in) pf1 = x4[(size_t)r * 281 + gj];
            }
        }

        // 2. two-level partial sums (read srow only)
        for (int i = tid; i < 4 * NF4; i += 256) {
            int q = i / NF4, j = i - q * NF4;
            float4 v = srow4[q][j];
            ps[q][j] = v.x + v.y + v.z + v.w;
        }
        if (tid < 4 * 19) {
            int q = tid / 19, j2 = tid - q * 19;
            float4 a0 = srow4[q][4*j2+0], a1 = srow4[q][4*j2+1];
            float4 a2 = srow4[q][4*j2+2], a3 = srow4[q][4*j2+3];
            pps[q][j2] = (a0.x+a0.y+a0.z+a0.w) + (a1.x+a1.y+a1.z+a1.w)
                       + (a2.x+a2.y+a2.z+a2.w) + (a3.x+a3.y+a3.z+a3.w);
        }
        __syncthreads();   // B1: ps/pps visible

        // 3. horizontal 100-sums -> f16 ring.  task (q, tp): cols c0+4tp..+3 of row ra+q
        if (tid < 208) {
            int q  = tid & 3;
            int tp = tid >> 2;                   // 0..51
            int r  = ra + q;
            if (r < r1_in) {
                // S = x[a..a+99], a = 4*c0a4 + 4*tp  (ps index tp..tp+24)
                int l   = (4 - (tp & 3)) & 3;
                int k   = (25 - l) >> 2;
                int rem = 25 - l - 4 * k;
                float S = 0.f;
                for (int i2 = 0; i2 < l; ++i2)   S += ps[q][tp + i2];
                int p0 = (tp + l) >> 2;
                for (int i2 = 0; i2 < k; ++i2)   S += pps[q][p0 + i2];
                for (int i2 = 0; i2 < rem; ++i2) S += ps[q][tp + l + 4*k + i2];

                float4 loa = srow4[q][tp],      lob = srow4[q][tp + 1];
                float4 hia = srow4[q][tp + 25], hib = srow4[q][tp + 26];
                float t0 = hia.x - loa.x, t1 = hia.y - loa.y, t2 = hia.z - loa.z;
                float t3 = hia.w - loa.w, t4 = hib.x - lob.x, t5 = hib.y - lob.y;

                float base, d0, d1, d2;          // slide to misalignment d (uniform)
                switch (d) {
                    case 0:  base = S;              d0 = t0; d1 = t1; d2 = t2; break;
                    case 1:  base = S + t0;         d0 = t1; d1 = t2; d2 = t3; break;
                    case 2:  base = S + t0 + t1;    d0 = t2; d1 = t3; d2 = t4; break;
                    default: base = S + t0 + t1 + t2; d0 = t3; d1 = t4; d2 = t5; break;
                }
                float h1 = base + d0, h2 = h1 + d1, h3 = h2 + d2;

                int slot = r % RSLOT;
                struct alignas(8) hh { _Float16 a, bb, c, dd; };
                *(hh*)&ring[slot][4 * tp] =
                    hh{ (_Float16)base, (_Float16)h1, (_Float16)h2, (_Float16)h3 };
            }
        }
        __syncthreads();   // B2: ring visible; all srow readers done

        // 4. vertical running sum + output (thread = one column)
        if (tid < SW) {
            #pragma unroll
            for (int q = 0; q < 4; ++q) {
                int r = ra + q;
                if (r >= r1_in) break;
                s += (float)ring[r % RSLOT][tid];
                if (r >= r0 + KWIN)
                    s -= (float)ring[(r - KWIN) % RSLOT][tid];
                if (r >= r0 + KWIN - 1) {
                    int i = r - (KWIN - 1);
                    out[((size_t)b * H_OUT + i) * W_OUT + c0 + tid] = s * scale;
                }
            }
        }

        // 5. commit prefetched chunk to srow (safe: srow readers done at B2)
        if (rb < r1_in) {
            if (tid < 4 * NF4) {
                int q = tid / NF4, j = tid - q * NF4;
                srow4[q][j] = pf0;
            }
            int i1 = tid + 256;
            if (i1 < 4 * NF4) {
                int q = i1 / NF4, j = i1 - q * NF4;
                srow4[q][j] = pf1;
            }
        }
        __syncthreads();   // B3: next srow visible; ring old-slots safe until next B2
    }
}

extern "C" void kernel_launch(void* const* d_in, const int* in_sizes, int n_in,
                              void* d_out, int out_size, void* d_ws, size_t ws_size,
                              hipStream_t stream) {
    const float* x = (const float*)d_in[0];
    float* out     = (float*)d_out;
    (void)d_ws; (void)ws_size;

    dim3 grid(NSTRIP, NBAND, 32);
    fused_box_kernel<<<grid, 256, 0, stream>>>(x, out);
}

// Round 5
// 119.786 us; speedup vs baseline: 2.2554x; 2.2554x over previous
//
#include <hip/hip_runtime.h>

// 100x100 sliding mean over x[32][1][1124][1124] f32 -> out[32][1][1025][1025] f32.
// Two passes. Pass H: horizontal 100-sum -> T (f16, padded stride) in d_ws.
// Pass V: vertical 100-sum + 1e-4 scale.
// Cache strategy: x is read-once -> nontemporal loads; out is write-once ->
// nontemporal stores; T (74 MB) stays Infinity-Cache-resident between passes,
// so pass V's reads are L3 hits and its HBM cost is just the output write.

#define H_IN    1124
#define W_IN    1124
#define KWIN    100
#define W_OUT   1025
#define H_OUT   1025
#define TSTR    1032   // T row stride in halves (2064 B, 16B-divisible)
#define NBANDS  13
#define BANDR   79     // 13*79 = 1027 >= 1025

typedef float    f32x4  __attribute__((ext_vector_type(4)));
typedef _Float16 f16x8  __attribute__((ext_vector_type(8)));

// ---------------- Pass H: one block per input row, T output in f16 ----------
__global__ __launch_bounds__(256) void hslide_kernel(
    const float* __restrict__ x,     // [g*1124][1124]
    _Float16* __restrict__ T)        // [g*1124][TSTR]
{
    __shared__ float    srow[W_IN];      // 1124
    __shared__ float    ps[282];         // 4-wide partial sums (281 used)
    __shared__ _Float16 sout[TSTR];      // 1025 used + 7 pad

    const int row = blockIdx.x;
    const int tid = threadIdx.x;
    const f32x4* xr4 = (const f32x4*)(x + (size_t)row * W_IN);

    // stage the row with nontemporal (stream-once) loads
    for (int i = tid; i < 281; i += 256)
        ((f32x4*)srow)[i] = __builtin_nontemporal_load(xr4 + i);
    __syncthreads();

    float4 lo = ((const float4*)srow)[tid];
    ps[tid] = lo.x + lo.y + lo.z + lo.w;
    if (tid < 25) {
        float4 v = ((const float4*)srow)[256 + tid];
        ps[256 + tid] = v.x + v.y + v.z + v.w;
    }
    if (tid < 7) sout[1025 + tid] = (_Float16)0.f;
    __syncthreads();

    {
        const int w0 = tid * 4;
        float s = 0.f;
        #pragma unroll
        for (int j = 0; j < 25; ++j) s += ps[tid + j];     // taps w0..w0+99
        float4 hi = ((const float4*)srow)[tid + 25];       // srow[w0+100..w0+103]
        float s1 = s  + hi.x - lo.x;
        float s2 = s1 + hi.y - lo.y;
        float s3 = s2 + hi.z - lo.z;
        struct alignas(8) hh { _Float16 a, b, c, d; };
        *reinterpret_cast<hh*>(&sout[w0]) =
            hh{ (_Float16)s, (_Float16)s1, (_Float16)s2, (_Float16)s3 };
        if (tid == 255) {
            float t = 0.f;
            #pragma unroll
            for (int j = 0; j < 25; ++j) t += ps[256 + j]; // taps 1024..1123
            sout[1024] = (_Float16)t;
        }
    }
    __syncthreads();

    // cached store of T row (we WANT T resident in L2/L3)
    f32x4* tr4 = (f32x4*)(T + (size_t)row * TSTR);
    if (tid < 129) tr4[tid] = ((const f32x4*)sout)[tid];
}

// ---------------- Pass V: 8 f16 cols/thread, deep MLP, NT output ------------
// grid (1, NBANDS, g), block 192; threads 0..128 active (129*8 = 1032 cols).
__global__ __launch_bounds__(192) void vslide_kernel(
    const _Float16* __restrict__ T,  // [g*1124][TSTR]
    float* __restrict__ out)         // [g][1025][1025]
{
    const int tid = threadIdx.x;
    if (tid > 128) return;
    const int band = blockIdx.y;
    const int b    = blockIdx.z;
    const int r0   = band * BANDR;
    const int nr   = min(BANDR, H_OUT - r0);
    if (nr <= 0) return;

    const int w0 = tid * 8;
    const _Float16* base = T + ((size_t)b * H_IN + r0) * TSTR + w0;  // 16B-aligned
    const float scale = 1.0f / (float)(KWIN * KWIN);
    const bool full = (tid < 128);

    float s[8];
    #pragma unroll
    for (int j = 0; j < 8; ++j) s[j] = 0.f;

    // prologue: 100 rows, batched 4 at a time (independent 16B loads -> MLP)
    {
        const _Float16* p = base;
        #pragma unroll 5
        for (int c = 0; c < 25; ++c) {
            f16x8 v0 = *(const f16x8*)(p);
            f16x8 v1 = *(const f16x8*)(p + TSTR);
            f16x8 v2 = *(const f16x8*)(p + 2 * TSTR);
            f16x8 v3 = *(const f16x8*)(p + 3 * TSTR);
            #pragma unroll
            for (int j = 0; j < 8; ++j)
                s[j] += ((float)v0[j] + (float)v1[j])
                      + ((float)v2[j] + (float)v3[j]);
            p += 4 * TSTR;
        }
    }

    float* q = out + ((size_t)b * H_OUT + r0) * W_OUT + w0;

    // emit out[r0]
    if (full) {
        #pragma unroll
        for (int j = 0; j < 8; ++j)
            __builtin_nontemporal_store(s[j] * scale, q + j);
    } else {
        __builtin_nontemporal_store(s[0] * scale, q);
    }
    q += W_OUT;

    // steady: add row r0+100+i, sub row r0+i, emit out[r0+1+i]
    const _Float16* padd = base + (size_t)KWIN * TSTR;
    const _Float16* psub = base;
    const int steps = nr - 1;
    #pragma unroll 4
    for (int i = 0; i < steps; ++i) {
        f16x8 a = *(const f16x8*)padd;  padd += TSTR;
        f16x8 d = *(const f16x8*)psub;  psub += TSTR;
        #pragma unroll
        for (int j = 0; j < 8; ++j)
            s[j] += (float)a[j] - (float)d[j];
        if (full) {
            #pragma unroll
            for (int j = 0; j < 8; ++j)
                __builtin_nontemporal_store(s[j] * scale, q + j);
        } else {
            __builtin_nontemporal_store(s[0] * scale, q);
        }
        q += W_OUT;
    }
}

extern "C" void kernel_launch(void* const* d_in, const int* in_sizes, int n_in,
                              void* d_out, int out_size, void* d_ws, size_t ws_size,
                              hipStream_t stream) {
    const float* x = (const float*)d_in[0];
    float* out     = (float*)d_out;
    _Float16* ws   = (_Float16*)d_ws;

    const int B = 32;
    const size_t perBatchT = (size_t)H_IN * TSTR * sizeof(_Float16);  // ~2.32 MB

    int G = (int)(ws_size / perBatchT);
    if (G > B) G = B;
    if (G < 1) G = 1;

    for (int b0 = 0; b0 < B; b0 += G) {
        const int g = (B - b0 < G) ? (B - b0) : G;

        hslide_kernel<<<g * H_IN, 256, 0, stream>>>(
            x + (size_t)b0 * H_IN * W_IN, ws);

        dim3 vgrid(1, NBANDS, g);
        vslide_kernel<<<vgrid, 192, 0, stream>>>(
            ws, out + (size_t)b0 * H_OUT * W_OUT);
    }
}